// Round 1
// baseline (523.444 us; speedup 1.0000x reference)
//
#include <hip/hip_runtime.h>
#include <math.h>

// Problem constants (match reference)
constexpr int B = 128;
constexpr int N = 512;
constexpr int DEG = 8;
constexpr int D = 128;
constexpr int E = B * N * DEG;         // 524288
constexpr int EPG = N * DEG;           // 4096 edges per graph
constexpr int NN = B * N;              // 65536 total nodes
constexpr int K1 = 410;                // ceil(0.8*512)
constexpr int K2 = 328;                // ceil(0.8*410)

// ---------------------------------------------------------------------------
// CSR build: per-graph counting sort of edges by dst. One block per graph.
// Edges of graph g are contiguous; all src/dst lie in [g*512,(g+1)*512).
// Built once per launch; reused by both convs (same edge list).
// ---------------------------------------------------------------------------
__global__ __launch_bounds__(512) void k_csr(const int* __restrict__ ei,
                                             int* __restrict__ coff,
                                             int* __restrict__ ccnt,
                                             int* __restrict__ csrc) {
    __shared__ int cnt[512];
    __shared__ int off[512];
    __shared__ int cur[512];
    const int g = blockIdx.x, t = threadIdx.x;
    const int base = g * N;
    const int* srcs = ei + g * EPG;          // ei[0:E] = src
    const int* dsts = ei + E + g * EPG;      // ei[E:2E] = dst
    cnt[t] = 0;
    __syncthreads();
    #pragma unroll
    for (int e = t; e < EPG; e += 512)
        atomicAdd(&cnt[dsts[e] - base], 1);
    __syncthreads();
    if (t == 0) {
        int acc = 0;
        for (int i = 0; i < 512; ++i) { off[i] = acc; acc += cnt[i]; }
    }
    __syncthreads();
    cur[t] = off[t];
    coff[base + t] = g * EPG + off[t];       // global position into csrc
    ccnt[base + t] = cnt[t];
    __syncthreads();
    #pragma unroll
    for (int e = t; e < EPG; e += 512) {
        int d = dsts[e] - base;
        int pos = atomicAdd(&cur[d], 1);
        csrc[g * EPG + pos] = srcs[e];       // store GLOBAL src node id
    }
}

// ---------------------------------------------------------------------------
// Gather-sum: agg[n] = sum_{e: dst==n} feat[src_e] * (gate ? gate[src_e] : 1)
// grid = B*4 blocks; each block: 128 nodes, 256 threads (8 nodes in flight,
// 32 lanes x float4 = full 512B row per node group).
// ---------------------------------------------------------------------------
__global__ __launch_bounds__(256) void k_gather(const float* __restrict__ feat,
                                                const float* __restrict__ gate,
                                                const int* __restrict__ coff,
                                                const int* __restrict__ ccnt,
                                                const int* __restrict__ csrc,
                                                float* __restrict__ aggout) {
    const int bid = blockIdx.x;
    const int g = bid >> 2, q = bid & 3;
    const int t = threadIdx.x;
    const int lane4 = t & 31, grp = t >> 5;          // grp in [0,8)
    const int fo = lane4 * 4;
    for (int it = 0; it < 16; ++it) {
        const int n = g * N + q * 128 + it * 8 + grp;
        const int start = coff[n];
        const int deg = ccnt[n];
        float4 acc = make_float4(0.f, 0.f, 0.f, 0.f);
        if (gate) {
            for (int k = 0; k < deg; ++k) {
                int idx = csrc[start + k];
                float gt = gate[idx];
                float4 v = *(const float4*)&feat[(size_t)idx * D + fo];
                acc.x += v.x * gt; acc.y += v.y * gt;
                acc.z += v.z * gt; acc.w += v.w * gt;
            }
        } else {
            for (int k = 0; k < deg; ++k) {
                int idx = csrc[start + k];
                float4 v = *(const float4*)&feat[(size_t)idx * D + fo];
                acc.x += v.x; acc.y += v.y; acc.z += v.z; acc.w += v.w;
            }
        }
        *(float4*)&aggout[(size_t)n * D + fo] = acc;
    }
}

// ---------------------------------------------------------------------------
// Fused conv GEMM: out = relu( (A0 .* gateA) @ W0 + A1 @ W1 + bias ),
// plus score epilogue sun[row] = out[row,:] . pvec  (for TopK pooling).
// M=65536, Ncols=128, K=128+128. BM=64, BN=128, BK=16; 256 threads;
// thread tile 8 rows x 4 cols.
// ---------------------------------------------------------------------------
__global__ __launch_bounds__(256) void k_gemm(const float* __restrict__ A0,
                                              const float* __restrict__ gateA,
                                              const float* __restrict__ A1,
                                              const float* __restrict__ W0,
                                              const float* __restrict__ W1,
                                              const float* __restrict__ bias,
                                              const float* __restrict__ pvec,
                                              float* __restrict__ out,
                                              float* __restrict__ sun) {
    __shared__ float As[64 * 16];
    __shared__ float Bs[16 * 128];
    __shared__ float red[64 * 33];
    const int t = threadIdx.x;
    const int r0 = blockIdx.x * 64;
    const int tx = t & 31;          // col group: cols [tx*4, tx*4+4)
    const int ty = t >> 5;          // row group: rows [ty*8, ty*8+8)
    const int arow = t >> 2, akk = (t & 3) * 4;   // A staging: 64x16
    const int brow = t >> 4, bcol = (t & 15) * 8; // B staging: 16x128
    const float g0 = gateA ? gateA[r0 + arow] : 1.0f;

    float acc[8][4] = {};
    for (int phase = 0; phase < 2; ++phase) {
        const float* Ap = phase ? A1 : A0;
        const float* Wp = phase ? W1 : W0;
        const float gmul = phase ? 1.0f : g0;
        for (int k0 = 0; k0 < D; k0 += 16) {
            float4 av = *(const float4*)&Ap[(size_t)(r0 + arow) * D + k0 + akk];
            av.x *= gmul; av.y *= gmul; av.z *= gmul; av.w *= gmul;
            *(float4*)&As[arow * 16 + akk] = av;
            float4 b0 = *(const float4*)&Wp[(size_t)(k0 + brow) * 128 + bcol];
            float4 b1 = *(const float4*)&Wp[(size_t)(k0 + brow) * 128 + bcol + 4];
            *(float4*)&Bs[brow * 128 + bcol] = b0;
            *(float4*)&Bs[brow * 128 + bcol + 4] = b1;
            __syncthreads();
            #pragma unroll
            for (int k = 0; k < 16; k += 4) {
                float4 bv0 = *(const float4*)&Bs[(k + 0) * 128 + tx * 4];
                float4 bv1 = *(const float4*)&Bs[(k + 1) * 128 + tx * 4];
                float4 bv2 = *(const float4*)&Bs[(k + 2) * 128 + tx * 4];
                float4 bv3 = *(const float4*)&Bs[(k + 3) * 128 + tx * 4];
                #pragma unroll
                for (int i = 0; i < 8; ++i) {
                    float4 a = *(const float4*)&As[(ty * 8 + i) * 16 + k];
                    acc[i][0] = fmaf(a.x, bv0.x, acc[i][0]);
                    acc[i][1] = fmaf(a.x, bv0.y, acc[i][1]);
                    acc[i][2] = fmaf(a.x, bv0.z, acc[i][2]);
                    acc[i][3] = fmaf(a.x, bv0.w, acc[i][3]);
                    acc[i][0] = fmaf(a.y, bv1.x, acc[i][0]);
                    acc[i][1] = fmaf(a.y, bv1.y, acc[i][1]);
                    acc[i][2] = fmaf(a.y, bv1.z, acc[i][2]);
                    acc[i][3] = fmaf(a.y, bv1.w, acc[i][3]);
                    acc[i][0] = fmaf(a.z, bv2.x, acc[i][0]);
                    acc[i][1] = fmaf(a.z, bv2.y, acc[i][1]);
                    acc[i][2] = fmaf(a.z, bv2.z, acc[i][2]);
                    acc[i][3] = fmaf(a.z, bv2.w, acc[i][3]);
                    acc[i][0] = fmaf(a.w, bv3.x, acc[i][0]);
                    acc[i][1] = fmaf(a.w, bv3.y, acc[i][1]);
                    acc[i][2] = fmaf(a.w, bv3.z, acc[i][2]);
                    acc[i][3] = fmaf(a.w, bv3.w, acc[i][3]);
                }
            }
            __syncthreads();
        }
    }
    // Epilogue: bias + relu + store + per-row score partials
    const float4 bb = *(const float4*)&bias[tx * 4];
    const float4 pv = *(const float4*)&pvec[tx * 4];
    #pragma unroll
    for (int i = 0; i < 8; ++i) {
        float4 v;
        v.x = fmaxf(acc[i][0] + bb.x, 0.f);
        v.y = fmaxf(acc[i][1] + bb.y, 0.f);
        v.z = fmaxf(acc[i][2] + bb.z, 0.f);
        v.w = fmaxf(acc[i][3] + bb.w, 0.f);
        *(float4*)&out[(size_t)(r0 + ty * 8 + i) * D + tx * 4] = v;
        red[(ty * 8 + i) * 33 + tx] = v.x * pv.x + v.y * pv.y + v.z * pv.z + v.w * pv.w;
    }
    __syncthreads();
    if (t < 64) {
        float s = 0.f;
        #pragma unroll
        for (int k = 0; k < 32; ++k) s += red[t * 33 + k];
        sun[r0 + t] = s;   // unnormalized score h . p  (normalize in topk)
    }
}

// ---------------------------------------------------------------------------
// Per-graph top-K: rank by (s_j > s_i) || (s_j==s_i && j<i) -- matches
// jax.lax.top_k stable tie-break. Also computes ||p|| and gate=tanh(s/||p||).
// One block (512 threads) per graph.
// ---------------------------------------------------------------------------
__global__ __launch_bounds__(512) void k_topk(const float* __restrict__ sun,
                                              const float* __restrict__ p,
                                              const float* __restrict__ prevmask,
                                              int K,
                                              float* __restrict__ gate,
                                              float* __restrict__ mask) {
    __shared__ float ls[512];
    __shared__ float red[128];
    __shared__ float norm_s;
    const int g = blockIdx.x, t = threadIdx.x;
    const int n = g * N + t;
    float s = sun[n];
    if (prevmask && prevmask[n] == 0.0f) s = -INFINITY;
    ls[t] = s;
    if (t < 128) { float pvv = p[t]; red[t] = pvv * pvv; }
    __syncthreads();
    for (int w = 64; w >= 1; w >>= 1) {
        if (t < w) red[t] += red[t + w];
        __syncthreads();
    }
    if (t == 0) norm_s = sqrtf(red[0]);
    __syncthreads();
    int cnt = 0;
    for (int j = 0; j < 512; ++j) {
        float sj = ls[j];
        cnt += (sj > s || (sj == s && j < t)) ? 1 : 0;
    }
    const bool keep = cnt < K;
    gate[n] = keep ? tanhf(s / norm_s) : 0.0f;
    mask[n] = keep ? 1.0f : 0.0f;
}

// ---------------------------------------------------------------------------
// Readout: xout[g][f]      = max over kept nodes of h[n][f]*gate[n]
//          xout[g][128+f]  = (sum over nodes of h[n][f]*gate[n]) / K
// One block (512 threads = 4 node-subsets x 128 feats) per graph.
// ---------------------------------------------------------------------------
__global__ __launch_bounds__(512) void k_readout(const float* __restrict__ h,
                                                 const float* __restrict__ gate,
                                                 const float* __restrict__ mask,
                                                 float invK,
                                                 float* __restrict__ xout) {
    __shared__ float smax[4][128];
    __shared__ float ssum[4][128];
    const int g = blockIdx.x, t = threadIdx.x;
    const int f = t & 127, sub = t >> 7;
    float vmax = -INFINITY, vsum = 0.f;
    for (int nl = sub; nl < N; nl += 4) {
        const int n = g * N + nl;
        const float gt = gate[n];
        const float v = h[(size_t)n * D + f] * gt;
        vsum += v;
        if (mask[n] != 0.f) vmax = fmaxf(vmax, v);
    }
    smax[sub][f] = vmax;
    ssum[sub][f] = vsum;
    __syncthreads();
    if (t < 128) {
        float m = fmaxf(fmaxf(smax[0][t], smax[1][t]), fmaxf(smax[2][t], smax[3][t]));
        float s = ssum[0][t] + ssum[1][t] + ssum[2][t] + ssum[3][t];
        xout[g * 256 + t] = m;
        xout[g * 256 + 128 + t] = s * invK;
    }
}

// ---------------------------------------------------------------------------
// MLP head: z = X1+X2 (256) -> relu(z@lw1+lb1) (128) -> relu(@lw2+lb2) (64)
// -> sigmoid(@lw3+lb3) (1). One block (128 threads) per graph.
// ---------------------------------------------------------------------------
__global__ __launch_bounds__(128) void k_mlp(const float* __restrict__ X1,
                                             const float* __restrict__ X2,
                                             const float* __restrict__ lw1,
                                             const float* __restrict__ lb1,
                                             const float* __restrict__ lw2,
                                             const float* __restrict__ lb2,
                                             const float* __restrict__ lw3,
                                             const float* __restrict__ lb3,
                                             float* __restrict__ out) {
    __shared__ float z[256];
    __shared__ float o1[128];
    __shared__ float o2p[64];
    const int g = blockIdx.x, t = threadIdx.x;
    z[t] = X1[g * 256 + t] + X2[g * 256 + t];
    z[t + 128] = X1[g * 256 + 128 + t] + X2[g * 256 + 128 + t];
    __syncthreads();
    float a = lb1[t];
    for (int i = 0; i < 256; ++i) a = fmaf(z[i], lw1[i * 128 + t], a);
    o1[t] = fmaxf(a, 0.f);
    __syncthreads();
    if (t < 64) {
        float b = lb2[t];
        for (int i = 0; i < 128; ++i) b = fmaf(o1[i], lw2[i * 64 + t], b);
        o2p[t] = fmaxf(b, 0.f) * lw3[t];
    }
    __syncthreads();
    if (t == 0) {
        float sacc = lb3[0];
        for (int i = 0; i < 64; ++i) sacc += o2p[i];
        out[g] = 1.f / (1.f + expf(-sacc));
    }
}

// ---------------------------------------------------------------------------
extern "C" void kernel_launch(void* const* d_in, const int* in_sizes, int n_in,
                              void* d_out, int out_size, void* d_ws, size_t ws_size,
                              hipStream_t stream) {
    const float* x    = (const float*)d_in[0];
    const int*   ei   = (const int*)d_in[1];
    const float* W1r  = (const float*)d_in[2];
    const float* W1n  = (const float*)d_in[3];
    const float* b1   = (const float*)d_in[4];
    const float* p1   = (const float*)d_in[5];
    const float* W2r  = (const float*)d_in[6];
    const float* W2n  = (const float*)d_in[7];
    const float* b2   = (const float*)d_in[8];
    const float* p2   = (const float*)d_in[9];
    const float* lw1  = (const float*)d_in[10];
    const float* lb1  = (const float*)d_in[11];
    const float* lw2  = (const float*)d_in[12];
    const float* lb2  = (const float*)d_in[13];
    const float* lw3  = (const float*)d_in[14];
    const float* lb3  = (const float*)d_in[15];
    float* out = (float*)d_out;

    // Workspace layout (~100 MB total)
    char* w = (char*)d_ws;
    float* h1  = (float*)w; w += (size_t)NN * D * 4;     // 33.5 MB
    float* h2  = (float*)w; w += (size_t)NN * D * 4;     // 33.5 MB
    float* agg = (float*)w; w += (size_t)NN * D * 4;     // 33.5 MB (reused conv1/conv2)
    int* coff  = (int*)w;   w += (size_t)NN * 4;
    int* ccnt  = (int*)w;   w += (size_t)NN * 4;
    int* csrc  = (int*)w;   w += (size_t)E * 4;
    float* sun = (float*)w; w += (size_t)NN * 4;         // reused for s1/s2
    float* g1  = (float*)w; w += (size_t)NN * 4;
    float* m1  = (float*)w; w += (size_t)NN * 4;
    float* g2  = (float*)w; w += (size_t)NN * 4;
    float* m2  = (float*)w; w += (size_t)NN * 4;
    float* X1  = (float*)w; w += (size_t)B * 256 * 4;
    float* X2  = (float*)w; w += (size_t)B * 256 * 4;

    // Build CSR once (shared by both convs)
    k_csr<<<B, 512, 0, stream>>>(ei, coff, ccnt, csrc);

    // conv1: h1 = relu(x@W1r + agg(x)@W1n + b1); s1 = h1.p1
    k_gather<<<B * 4, 256, 0, stream>>>(x, nullptr, coff, ccnt, csrc, agg);
    k_gemm<<<NN / 64, 256, 0, stream>>>(x, nullptr, agg, W1r, W1n, b1, p1, h1, sun);
    k_topk<<<B, 512, 0, stream>>>(sun, p1, nullptr, K1, g1, m1);
    k_readout<<<B, 512, 0, stream>>>(h1, g1, m1, 1.0f / (float)K1, X1);

    // conv2: h2 = relu((h1.*g1)@W2r + agg(h1.*g1)@W2n + b2); s2 = h2.p2
    k_gather<<<B * 4, 256, 0, stream>>>(h1, g1, coff, ccnt, csrc, agg);
    k_gemm<<<NN / 64, 256, 0, stream>>>(h1, g1, agg, W2r, W2n, b2, p2, h2, sun);
    k_topk<<<B, 512, 0, stream>>>(sun, p2, m1, K2, g2, m2);
    k_readout<<<B, 512, 0, stream>>>(h2, g2, m2, 1.0f / (float)K2, X2);

    // MLP head
    k_mlp<<<B, 128, 0, stream>>>(X1, X2, lw1, lb1, lw2, lb2, lw3, lb3, out);
}

// Round 2
// 371.378 us; speedup vs baseline: 1.4095x; 1.4095x over previous
//
#include <hip/hip_runtime.h>
#include <math.h>

// Problem constants (match reference)
constexpr int B = 128;
constexpr int N = 512;
constexpr int DEG = 8;
constexpr int D = 128;
constexpr int E = B * N * DEG;         // 524288
constexpr int EPG = N * DEG;           // 4096 edges per graph
constexpr int NN = B * N;              // 65536 total nodes
constexpr int K1 = 410;                // ceil(0.8*512)
constexpr int K2 = 328;                // ceil(0.8*410)

// ---------------------------------------------------------------------------
// CSR build: per-graph counting sort of edges by dst. One block per graph.
// Hillis-Steele scan replaces the serial t==0 prefix loop.
// ---------------------------------------------------------------------------
__global__ __launch_bounds__(512) void k_csr(const int* __restrict__ ei,
                                             int* __restrict__ coff,
                                             int* __restrict__ ccnt,
                                             int* __restrict__ csrc) {
    __shared__ int cnt[512];
    __shared__ int sa[512];
    __shared__ int cur[512];
    const int g = blockIdx.x, t = threadIdx.x;
    const int base = g * N;
    const int* srcs = ei + g * EPG;          // ei[0:E] = src
    const int* dsts = ei + E + g * EPG;      // ei[E:2E] = dst
    cnt[t] = 0;
    __syncthreads();
    #pragma unroll
    for (int e = t; e < EPG; e += 512)
        atomicAdd(&cnt[dsts[e] - base], 1);
    __syncthreads();
    int v = cnt[t];
    sa[t] = v;
    __syncthreads();
    for (int d = 1; d < 512; d <<= 1) {
        int add = (t >= d) ? sa[t - d] : 0;
        __syncthreads();
        sa[t] += add;
        __syncthreads();
    }
    const int excl = sa[t] - v;              // exclusive prefix
    cur[t] = excl;
    coff[base + t] = g * EPG + excl;         // global position into csrc
    ccnt[base + t] = v;
    __syncthreads();
    #pragma unroll
    for (int e = t; e < EPG; e += 512) {
        int d = dsts[e] - base;
        int pos = atomicAdd(&cur[d], 1);
        csrc[g * EPG + pos] = srcs[e];       // store GLOBAL src node id
    }
}

// ---------------------------------------------------------------------------
// Gather-sum: agg[n] = sum_{e: dst==n} feat[src_e] * (gate ? gate[src_e] : 1)
// 2048 blocks x 256 threads (100% occupancy cap). XCD-aware swizzle: all 16
// blocks of one graph share bid&7 so (with round-robin block->XCD dispatch)
// a graph's 256KB feature chunk stays in one XCD's L2.
// ---------------------------------------------------------------------------
__global__ __launch_bounds__(256) void k_gather(const float* __restrict__ feat,
                                                const float* __restrict__ gate,
                                                const int* __restrict__ coff,
                                                const int* __restrict__ ccnt,
                                                const int* __restrict__ csrc,
                                                float* __restrict__ aggout) {
    const int bid = blockIdx.x;
    const int xcd = bid & 7;
    const int j = bid >> 3;                  // 0..255
    const int g = ((j & 15) << 3) | xcd;     // 0..127, fixed xcd per graph
    const int chunk = j >> 4;                // 0..15, 32 nodes per chunk
    const int t = threadIdx.x;
    const int lane = t & 31, grp = t >> 5;   // grp in [0,8)
    const int fo = lane * 4;
    #pragma unroll
    for (int it = 0; it < 4; ++it) {
        const int n = g * N + chunk * 32 + it * 8 + grp;
        const int start = coff[n];
        const int deg = ccnt[n];
        float4 acc = make_float4(0.f, 0.f, 0.f, 0.f);
        if (deg > 0) {
            int idx = csrc[start];
            if (gate) {
                for (int k = 0; k < deg; ++k) {
                    int nidx = (k + 1 < deg) ? csrc[start + k + 1] : 0;
                    float gt = gate[idx];
                    float4 v = *(const float4*)&feat[(size_t)idx * D + fo];
                    acc.x += v.x * gt; acc.y += v.y * gt;
                    acc.z += v.z * gt; acc.w += v.w * gt;
                    idx = nidx;
                }
            } else {
                for (int k = 0; k < deg; ++k) {
                    int nidx = (k + 1 < deg) ? csrc[start + k + 1] : 0;
                    float4 v = *(const float4*)&feat[(size_t)idx * D + fo];
                    acc.x += v.x; acc.y += v.y; acc.z += v.z; acc.w += v.w;
                    idx = nidx;
                }
            }
        }
        *(float4*)&aggout[(size_t)n * D + fo] = acc;
    }
}

// ---------------------------------------------------------------------------
// Fused conv GEMM: out = relu( (A0 .* gateA) @ W0 + A1 @ W1 + bias ),
// plus score epilogue sun[row] = out[row,:] . pvec.
// BM=64, BN=128, BK=32; 256 threads; thread tile 4 rows x 8 cols.
// A staged TRANSPOSED in LDS ([k][row], pad 68) -> conflict-free float4
// reads for both operands. 1024 blocks.
// ---------------------------------------------------------------------------
__global__ __launch_bounds__(256) void k_gemm(const float* __restrict__ A0,
                                              const float* __restrict__ gateA,
                                              const float* __restrict__ A1,
                                              const float* __restrict__ W0,
                                              const float* __restrict__ W1,
                                              const float* __restrict__ bias,
                                              const float* __restrict__ pvec,
                                              float* __restrict__ out,
                                              float* __restrict__ sun) {
    __shared__ float As[32 * 68];   // [k][row], padded row-dim 64->68
    __shared__ float Bs[32 * 128];  // [k][col]
    __shared__ float red[64 * 17];
    const int t = threadIdx.x;
    const int r0 = blockIdx.x * 64;
    const int tx = t & 15;          // cols [tx*8, tx*8+8)
    const int ty = t >> 4;          // rows [ty*4, ty*4+4)
    const int arow = t >> 2, acol0 = (t & 3) * 8;   // A staging: 64 rows x 32 k
    const int brow = t >> 3, bcol0 = (t & 7) * 16;  // B staging: 32 k x 128 cols
    const float grow = gateA ? gateA[r0 + arow] : 1.0f;

    float acc[4][8] = {};
    for (int phase = 0; phase < 2; ++phase) {
        const float* Ap = phase ? A1 : A0;
        const float* Wp = phase ? W1 : W0;
        const float gmul = phase ? 1.0f : grow;
        for (int k0 = 0; k0 < D; k0 += 32) {
            #pragma unroll
            for (int i = 0; i < 2; ++i) {
                float4 av = *(const float4*)&Ap[(size_t)(r0 + arow) * D + k0 + acol0 + i * 4];
                av.x *= gmul; av.y *= gmul; av.z *= gmul; av.w *= gmul;
                As[(acol0 + i * 4 + 0) * 68 + arow] = av.x;
                As[(acol0 + i * 4 + 1) * 68 + arow] = av.y;
                As[(acol0 + i * 4 + 2) * 68 + arow] = av.z;
                As[(acol0 + i * 4 + 3) * 68 + arow] = av.w;
            }
            #pragma unroll
            for (int i = 0; i < 4; ++i) {
                *(float4*)&Bs[brow * 128 + bcol0 + i * 4] =
                    *(const float4*)&Wp[(size_t)(k0 + brow) * 128 + bcol0 + i * 4];
            }
            __syncthreads();
            #pragma unroll 8
            for (int k = 0; k < 32; ++k) {
                float4 a  = *(const float4*)&As[k * 68 + ty * 4];
                float4 b0 = *(const float4*)&Bs[k * 128 + tx * 8];
                float4 b1 = *(const float4*)&Bs[k * 128 + tx * 8 + 4];
                float av4[4] = {a.x, a.y, a.z, a.w};
                float bv[8]  = {b0.x, b0.y, b0.z, b0.w, b1.x, b1.y, b1.z, b1.w};
                #pragma unroll
                for (int r = 0; r < 4; ++r)
                    #pragma unroll
                    for (int c = 0; c < 8; ++c)
                        acc[r][c] = fmaf(av4[r], bv[c], acc[r][c]);
            }
            __syncthreads();
        }
    }
    // Epilogue: bias + relu + store + per-row score partials
    float bb[8], pv[8];
    #pragma unroll
    for (int c = 0; c < 8; ++c) { bb[c] = bias[tx * 8 + c]; pv[c] = pvec[tx * 8 + c]; }
    #pragma unroll
    for (int r = 0; r < 4; ++r) {
        const int row = r0 + ty * 4 + r;
        float v[8]; float part = 0.f;
        #pragma unroll
        for (int c = 0; c < 8; ++c) {
            v[c] = fmaxf(acc[r][c] + bb[c], 0.f);
            part += v[c] * pv[c];
        }
        float4 s0 = make_float4(v[0], v[1], v[2], v[3]);
        float4 s1 = make_float4(v[4], v[5], v[6], v[7]);
        *(float4*)&out[(size_t)row * D + tx * 8]     = s0;
        *(float4*)&out[(size_t)row * D + tx * 8 + 4] = s1;
        red[(ty * 4 + r) * 17 + tx] = part;
    }
    __syncthreads();
    if (t < 64) {
        float s = 0.f;
        #pragma unroll
        for (int k = 0; k < 16; ++k) s += red[t * 17 + k];
        sun[r0 + t] = s;   // unnormalized score h . p (normalize in topk)
    }
}

// ---------------------------------------------------------------------------
// Per-graph top-K: rank by (s_j > s_i) || (s_j==s_i && j<i) -- matches
// jax.lax.top_k stable tie-break. Also computes ||p|| and gate=tanh(s/||p||).
// ---------------------------------------------------------------------------
__global__ __launch_bounds__(512) void k_topk(const float* __restrict__ sun,
                                              const float* __restrict__ p,
                                              const float* __restrict__ prevmask,
                                              int K,
                                              float* __restrict__ gate,
                                              float* __restrict__ mask) {
    __shared__ float ls[512];
    __shared__ float red[128];
    __shared__ float norm_s;
    const int g = blockIdx.x, t = threadIdx.x;
    const int n = g * N + t;
    float s = sun[n];
    if (prevmask && prevmask[n] == 0.0f) s = -INFINITY;
    ls[t] = s;
    if (t < 128) { float pvv = p[t]; red[t] = pvv * pvv; }
    __syncthreads();
    for (int w = 64; w >= 1; w >>= 1) {
        if (t < w) red[t] += red[t + w];
        __syncthreads();
    }
    if (t == 0) norm_s = sqrtf(red[0]);
    __syncthreads();
    int cnt = 0;
    for (int j = 0; j < 512; ++j) {
        float sj = ls[j];
        cnt += (sj > s || (sj == s && j < t)) ? 1 : 0;
    }
    const bool keep = cnt < K;
    gate[n] = keep ? tanhf(s / norm_s) : 0.0f;
    mask[n] = keep ? 1.0f : 0.0f;
}

// ---------------------------------------------------------------------------
// Readout: xout[g][f]      = max over kept nodes of h[n][f]*gate[n]
//          xout[g][128+f]  = (sum over nodes of h[n][f]*gate[n]) / K
// One block (1024 threads = 8 node-subsets x 128 feats) per graph.
// ---------------------------------------------------------------------------
__global__ __launch_bounds__(1024) void k_readout(const float* __restrict__ h,
                                                  const float* __restrict__ gate,
                                                  const float* __restrict__ mask,
                                                  float invK,
                                                  float* __restrict__ xout) {
    __shared__ float smax[8][128];
    __shared__ float ssum[8][128];
    const int g = blockIdx.x, t = threadIdx.x;
    const int f = t & 127, sub = t >> 7;
    float vmax = -INFINITY, vsum = 0.f;
    for (int nl = sub; nl < N; nl += 8) {
        const int n = g * N + nl;
        const float gt = gate[n];
        const float v = h[(size_t)n * D + f] * gt;
        vsum += v;
        if (mask[n] != 0.f) vmax = fmaxf(vmax, v);
    }
    smax[sub][f] = vmax;
    ssum[sub][f] = vsum;
    __syncthreads();
    if (t < 128) {
        float m = smax[0][t], s = ssum[0][t];
        #pragma unroll
        for (int k = 1; k < 8; ++k) { m = fmaxf(m, smax[k][t]); s += ssum[k][t]; }
        xout[g * 256 + t] = m;
        xout[g * 256 + 128 + t] = s * invK;
    }
}

// ---------------------------------------------------------------------------
// MLP head: z = X1+X2 (256) -> relu(z@lw1+lb1) (128) -> relu(@lw2+lb2) (64)
// -> sigmoid(@lw3+lb3) (1). One block (128 threads) per graph.
// ---------------------------------------------------------------------------
__global__ __launch_bounds__(128) void k_mlp(const float* __restrict__ X1,
                                             const float* __restrict__ X2,
                                             const float* __restrict__ lw1,
                                             const float* __restrict__ lb1,
                                             const float* __restrict__ lw2,
                                             const float* __restrict__ lb2,
                                             const float* __restrict__ lw3,
                                             const float* __restrict__ lb3,
                                             float* __restrict__ out) {
    __shared__ float z[256];
    __shared__ float o1[128];
    __shared__ float o2p[64];
    const int g = blockIdx.x, t = threadIdx.x;
    z[t] = X1[g * 256 + t] + X2[g * 256 + t];
    z[t + 128] = X1[g * 256 + 128 + t] + X2[g * 256 + 128 + t];
    __syncthreads();
    float a = lb1[t];
    for (int i = 0; i < 256; ++i) a = fmaf(z[i], lw1[i * 128 + t], a);
    o1[t] = fmaxf(a, 0.f);
    __syncthreads();
    if (t < 64) {
        float b = lb2[t];
        for (int i = 0; i < 128; ++i) b = fmaf(o1[i], lw2[i * 64 + t], b);
        o2p[t] = fmaxf(b, 0.f) * lw3[t];
    }
    __syncthreads();
    if (t == 0) {
        float sacc = lb3[0];
        for (int i = 0; i < 64; ++i) sacc += o2p[i];
        out[g] = 1.f / (1.f + expf(-sacc));
    }
}

// ---------------------------------------------------------------------------
extern "C" void kernel_launch(void* const* d_in, const int* in_sizes, int n_in,
                              void* d_out, int out_size, void* d_ws, size_t ws_size,
                              hipStream_t stream) {
    const float* x    = (const float*)d_in[0];
    const int*   ei   = (const int*)d_in[1];
    const float* W1r  = (const float*)d_in[2];
    const float* W1n  = (const float*)d_in[3];
    const float* b1   = (const float*)d_in[4];
    const float* p1   = (const float*)d_in[5];
    const float* W2r  = (const float*)d_in[6];
    const float* W2n  = (const float*)d_in[7];
    const float* b2   = (const float*)d_in[8];
    const float* p2   = (const float*)d_in[9];
    const float* lw1  = (const float*)d_in[10];
    const float* lb1  = (const float*)d_in[11];
    const float* lw2  = (const float*)d_in[12];
    const float* lb2  = (const float*)d_in[13];
    const float* lw3  = (const float*)d_in[14];
    const float* lb3  = (const float*)d_in[15];
    float* out = (float*)d_out;

    // Workspace layout (~110 MB total)
    char* w = (char*)d_ws;
    float* h1  = (float*)w; w += (size_t)NN * D * 4;
    float* h2  = (float*)w; w += (size_t)NN * D * 4;
    float* agg = (float*)w; w += (size_t)NN * D * 4;
    int* coff  = (int*)w;   w += (size_t)NN * 4;
    int* ccnt  = (int*)w;   w += (size_t)NN * 4;
    int* csrc  = (int*)w;   w += (size_t)E * 4;
    float* sun = (float*)w; w += (size_t)NN * 4;
    float* g1  = (float*)w; w += (size_t)NN * 4;
    float* m1  = (float*)w; w += (size_t)NN * 4;
    float* g2  = (float*)w; w += (size_t)NN * 4;
    float* m2  = (float*)w; w += (size_t)NN * 4;
    float* X1  = (float*)w; w += (size_t)B * 256 * 4;
    float* X2  = (float*)w; w += (size_t)B * 256 * 4;

    // Build CSR once (shared by both convs)
    k_csr<<<B, 512, 0, stream>>>(ei, coff, ccnt, csrc);

    // conv1: h1 = relu(x@W1r + agg(x)@W1n + b1); s1 = h1.p1
    k_gather<<<2048, 256, 0, stream>>>(x, nullptr, coff, ccnt, csrc, agg);
    k_gemm<<<NN / 64, 256, 0, stream>>>(x, nullptr, agg, W1r, W1n, b1, p1, h1, sun);
    k_topk<<<B, 512, 0, stream>>>(sun, p1, nullptr, K1, g1, m1);
    k_readout<<<B, 1024, 0, stream>>>(h1, g1, m1, 1.0f / (float)K1, X1);

    // conv2: h2 = relu((h1.*g1)@W2r + agg(h1.*g1)@W2n + b2); s2 = h2.p2
    k_gather<<<2048, 256, 0, stream>>>(h1, g1, coff, ccnt, csrc, agg);
    k_gemm<<<NN / 64, 256, 0, stream>>>(h1, g1, agg, W2r, W2n, b2, p2, h2, sun);
    k_topk<<<B, 512, 0, stream>>>(sun, p2, m1, K2, g2, m2);
    k_readout<<<B, 1024, 0, stream>>>(h2, g2, m2, 1.0f / (float)K2, X2);

    // MLP head
    k_mlp<<<B, 128, 0, stream>>>(X1, X2, lw1, lb1, lw2, lb2, lw3, lb3, out);
}

// Round 4
// 366.140 us; speedup vs baseline: 1.4296x; 1.0143x over previous
//
#include <hip/hip_runtime.h>
#include <math.h>

// Problem constants (match reference)
constexpr int B = 128;
constexpr int N = 512;
constexpr int DEG = 8;
constexpr int D = 128;
constexpr int E = B * N * DEG;         // 524288
constexpr int EPG = N * DEG;           // 4096 edges per graph
constexpr int NN = B * N;              // 65536 total nodes
constexpr int K1 = 410;                // ceil(0.8*512)
constexpr int K2 = 328;                // ceil(0.8*410)
constexpr int PADDEG = 16;             // fixed-degree padding for gather

// ---------------------------------------------------------------------------
// CSR build: per-graph counting sort of edges by dst. One block per graph.
// Emits variable CSR (coff/ccnt/csrc) + PADDED fixed-degree(16) CSR csrcp
// (pad slots = self-index, weighted 0 by gather; deg>16 tail stays in csrc).
// BUGFIX vs round 3: padded write uses NODE-LOCAL slot lpos = pos - offs[d],
// not the graph-global position pos.
// ---------------------------------------------------------------------------
__global__ __launch_bounds__(512) void k_csr2(const int* __restrict__ ei,
                                              int* __restrict__ coff,
                                              int* __restrict__ ccnt,
                                              int* __restrict__ csrc,
                                              int* __restrict__ csrcp) {
    __shared__ int cnt[512];
    __shared__ int sa[512];
    __shared__ int offs[512];
    __shared__ int cur[512];
    const int g = blockIdx.x, t = threadIdx.x;
    const int base = g * N;
    const int* srcs = ei + g * EPG;          // ei[0:E] = src
    const int* dsts = ei + E + g * EPG;      // ei[E:2E] = dst
    // init padded CSR with self-index (weight 0 in gather)
    {
        const int n = base + t;
        int4 self = make_int4(n, n, n, n);
        #pragma unroll
        for (int k4 = 0; k4 < PADDEG / 4; ++k4)
            *(int4*)&csrcp[(size_t)n * PADDEG + k4 * 4] = self;
    }
    cnt[t] = 0;
    __syncthreads();
    #pragma unroll
    for (int e = t; e < EPG; e += 512)
        atomicAdd(&cnt[dsts[e] - base], 1);
    __syncthreads();
    int v = cnt[t];
    sa[t] = v;
    __syncthreads();
    for (int d = 1; d < 512; d <<= 1) {
        int add = (t >= d) ? sa[t - d] : 0;
        __syncthreads();
        sa[t] += add;
        __syncthreads();
    }
    const int excl = sa[t] - v;              // exclusive prefix within graph
    offs[t] = excl;
    cur[t] = excl;
    coff[base + t] = g * EPG + excl;         // global position into csrc
    ccnt[base + t] = v;
    __syncthreads();
    #pragma unroll
    for (int e = t; e < EPG; e += 512) {
        int d = dsts[e] - base;
        int pos = atomicAdd(&cur[d], 1);     // graph-global slot
        int s = srcs[e];
        csrc[g * EPG + pos] = s;             // full list (order-consistent)
        int lpos = pos - offs[d];            // node-local slot
        if (lpos < PADDEG) csrcp[(size_t)(base + d) * PADDEG + lpos] = s;
    }
}

// ---------------------------------------------------------------------------
// Gather-sum via padded CSR: agg[n] = sum_k w_k * feat[idx_k],
// w_k = (k<deg) ? (gate?gate[idx_k]:1) : 0.  All 16 idx loaded up-front
// (4x int4) -> 16 independent feature loads; overflow loop for deg>16.
// 2048 blocks x 256 threads; XCD swizzle keeps a graph on one XCD's L2.
// ---------------------------------------------------------------------------
__global__ __launch_bounds__(256, 2) void k_gather(const float* __restrict__ feat,
                                                   const float* __restrict__ gate,
                                                   const int* __restrict__ coff,
                                                   const int* __restrict__ ccnt,
                                                   const int* __restrict__ csrc,
                                                   const int* __restrict__ csrcp,
                                                   float* __restrict__ aggout) {
    const int bid = blockIdx.x;
    const int xcd = bid & 7;
    const int j = bid >> 3;                  // 0..255
    const int g = ((j & 15) << 3) | xcd;     // 0..127, fixed xcd per graph
    const int chunk = j >> 4;                // 0..15, 32 nodes per chunk
    const int t = threadIdx.x;
    const int lane = t & 31, grp = t >> 5;   // grp in [0,8)
    const int fo = lane * 4;
    #pragma unroll
    for (int it = 0; it < 4; ++it) {
        const int n = g * N + chunk * 32 + it * 8 + grp;
        const int deg = ccnt[n];
        int idx[PADDEG];
        *(int4*)&idx[0]  = *(const int4*)&csrcp[(size_t)n * PADDEG + 0];
        *(int4*)&idx[4]  = *(const int4*)&csrcp[(size_t)n * PADDEG + 4];
        *(int4*)&idx[8]  = *(const int4*)&csrcp[(size_t)n * PADDEG + 8];
        *(int4*)&idx[12] = *(const int4*)&csrcp[(size_t)n * PADDEG + 12];
        float w[PADDEG];
        #pragma unroll
        for (int k = 0; k < PADDEG; ++k)
            w[k] = (k < deg) ? (gate ? gate[idx[k]] : 1.0f) : 0.0f;
        float4 acc = make_float4(0.f, 0.f, 0.f, 0.f);
        #pragma unroll
        for (int k = 0; k < PADDEG; ++k) {
            float4 v = *(const float4*)&feat[(size_t)idx[k] * D + fo];
            acc.x = fmaf(v.x, w[k], acc.x);
            acc.y = fmaf(v.y, w[k], acc.y);
            acc.z = fmaf(v.z, w[k], acc.z);
            acc.w = fmaf(v.w, w[k], acc.w);
        }
        if (deg > PADDEG) {                  // rare tail
            const int start = coff[n];
            for (int k = PADDEG; k < deg; ++k) {
                int ix = csrc[start + k];
                float gt = gate ? gate[ix] : 1.0f;
                float4 v = *(const float4*)&feat[(size_t)ix * D + fo];
                acc.x = fmaf(v.x, gt, acc.x);
                acc.y = fmaf(v.y, gt, acc.y);
                acc.z = fmaf(v.z, gt, acc.z);
                acc.w = fmaf(v.w, gt, acc.w);
            }
        }
        *(float4*)&aggout[(size_t)n * D + fo] = acc;
    }
}

// ---------------------------------------------------------------------------
// Fused conv GEMM: out = relu( (A0 .* gateA) @ W0 + A1 @ W1 + bias ),
// plus score epilogue sun[row] = out[row,:] . pvec.
// BM=128, BN=128, BK=32; 256 threads; 8x8 thread tile (rows ty*4+{0..3},
// 64+ty*4+{0..3}; cols tx*4+{0..3}, 64+tx*4+{0..3}).
// A staged transposed [k][row] stride 132; B staged [k][col] stride 128.
// All LDS read/write patterns are <=2-way (free on gfx950). 512 blocks.
// ---------------------------------------------------------------------------
__global__ __launch_bounds__(256, 2) void k_gemm(const float* __restrict__ A0,
                                                 const float* __restrict__ gateA,
                                                 const float* __restrict__ A1,
                                                 const float* __restrict__ W0,
                                                 const float* __restrict__ W1,
                                                 const float* __restrict__ bias,
                                                 const float* __restrict__ pvec,
                                                 float* __restrict__ out,
                                                 float* __restrict__ sun) {
    __shared__ float As[32 * 132];   // [k][row], row-dim padded 128->132
    __shared__ float Bs[32 * 128];   // [k][col]
    __shared__ float red[128 * 17];
    const int t = threadIdx.x;
    const int r0 = blockIdx.x * 128;
    const int tx = t & 15;           // col base tx*4 (+64)
    const int ty = t >> 4;           // row base ty*4 (+64)
    const int sar = t >> 1, sak = (t & 1) * 16;     // A staging: 128 rows x 32 k
    const int sbr = t >> 5, sbc = (t & 31) * 4;     // B staging: 32 k x 128 cols
    const float ga = gateA ? gateA[r0 + sar] : 1.0f;

    float acc[8][8] = {};
    for (int phase = 0; phase < 2; ++phase) {
        const float* Ap = phase ? A1 : A0;
        const float* Wp = phase ? W1 : W0;
        const float gmul = phase ? 1.0f : ga;
        for (int k0 = 0; k0 < D; k0 += 32) {
            #pragma unroll
            for (int i = 0; i < 4; ++i) {
                float4 av = *(const float4*)&Ap[(size_t)(r0 + sar) * D + k0 + sak + i * 4];
                av.x *= gmul; av.y *= gmul; av.z *= gmul; av.w *= gmul;
                As[(sak + i * 4 + 0) * 132 + sar] = av.x;
                As[(sak + i * 4 + 1) * 132 + sar] = av.y;
                As[(sak + i * 4 + 2) * 132 + sar] = av.z;
                As[(sak + i * 4 + 3) * 132 + sar] = av.w;
            }
            #pragma unroll
            for (int i = 0; i < 4; ++i) {
                *(float4*)&Bs[(sbr + i * 8) * 128 + sbc] =
                    *(const float4*)&Wp[(size_t)(k0 + sbr + i * 8) * 128 + sbc];
            }
            __syncthreads();
            #pragma unroll 8
            for (int k = 0; k < 32; ++k) {
                float4 a0 = *(const float4*)&As[k * 132 + ty * 4];
                float4 a1 = *(const float4*)&As[k * 132 + 64 + ty * 4];
                float4 b0 = *(const float4*)&Bs[k * 128 + tx * 4];
                float4 b1 = *(const float4*)&Bs[k * 128 + 64 + tx * 4];
                float av[8] = {a0.x, a0.y, a0.z, a0.w, a1.x, a1.y, a1.z, a1.w};
                float bv[8] = {b0.x, b0.y, b0.z, b0.w, b1.x, b1.y, b1.z, b1.w};
                #pragma unroll
                for (int r = 0; r < 8; ++r)
                    #pragma unroll
                    for (int c = 0; c < 8; ++c)
                        acc[r][c] = fmaf(av[r], bv[c], acc[r][c]);
            }
            __syncthreads();
        }
    }
    // Epilogue: bias + relu + store + per-row score partials
    float bb[8], pv[8];
    #pragma unroll
    for (int c = 0; c < 8; ++c) {
        const int col = (c < 4) ? (tx * 4 + c) : (64 + tx * 4 + c - 4);
        bb[c] = bias[col]; pv[c] = pvec[col];
    }
    #pragma unroll
    for (int r = 0; r < 8; ++r) {
        const int rl = (r < 4) ? (ty * 4 + r) : (64 + ty * 4 + r - 4);
        const int row = r0 + rl;
        float v[8]; float part = 0.f;
        #pragma unroll
        for (int c = 0; c < 8; ++c) {
            v[c] = fmaxf(acc[r][c] + bb[c], 0.f);
            part += v[c] * pv[c];
        }
        *(float4*)&out[(size_t)row * D + tx * 4]      = make_float4(v[0], v[1], v[2], v[3]);
        *(float4*)&out[(size_t)row * D + 64 + tx * 4] = make_float4(v[4], v[5], v[6], v[7]);
        red[rl * 17 + tx] = part;
    }
    __syncthreads();
    if (t < 128) {
        float s = 0.f;
        #pragma unroll
        for (int k = 0; k < 16; ++k) s += red[t * 17 + k];
        sun[r0 + t] = s;   // unnormalized score h . p (normalize in topk)
    }
}

// ---------------------------------------------------------------------------
// Fused per-graph TopK + readout. One block (1024 threads) per graph.
// TopK rank: cnt of (s_j > s_i) || (s_j==s_i && j<i)  (jax.lax.top_k order).
// gate = tanh(s/||p||) * keep; readout uses LDS-resident gate/mask.
// ---------------------------------------------------------------------------
__global__ __launch_bounds__(1024) void k_topk_readout(const float* __restrict__ sun,
                                                       const float* __restrict__ p,
                                                       const float* __restrict__ prevmask,
                                                       int K, float invK,
                                                       const float* __restrict__ h,
                                                       float* __restrict__ gate,
                                                       float* __restrict__ mask,
                                                       float* __restrict__ xout) {
    __shared__ float ls[512];
    __shared__ float lg[512];
    __shared__ float lm[512];
    __shared__ float red[128];
    __shared__ float smax[8][128];
    __shared__ float ssum[8][128];
    __shared__ float norm_s;
    const int g = blockIdx.x, t = threadIdx.x;
    if (t < 512) {
        const int n = g * N + t;
        float s = sun[n];
        if (prevmask && prevmask[n] == 0.0f) s = -INFINITY;
        ls[t] = s;
    }
    if (t < 128) { float pvv = p[t]; red[t] = pvv * pvv; }
    __syncthreads();
    if (t < 64) red[t] += red[t + 64];
    __syncthreads();
    if (t < 32) red[t] += red[t + 32];
    __syncthreads();
    if (t == 0) {
        float s = 0.f;
        #pragma unroll
        for (int i = 0; i < 32; ++i) s += red[i];
        norm_s = sqrtf(s);
    }
    __syncthreads();
    if (t < 512) {
        const float s = ls[t];
        int cnt = 0;
        for (int jj = 0; jj < 512; ++jj) {
            float sj = ls[jj];
            cnt += (sj > s || (sj == s && jj < t)) ? 1 : 0;
        }
        const bool keep = cnt < K;
        const float gv = keep ? tanhf(s / norm_s) : 0.0f;
        const float mv = keep ? 1.0f : 0.0f;
        lg[t] = gv; lm[t] = mv;
        gate[g * N + t] = gv; mask[g * N + t] = mv;
    }
    __syncthreads();
    const int f = t & 127, sub = t >> 7;
    float vmax = -INFINITY, vsum = 0.f;
    for (int nl = sub; nl < N; nl += 8) {
        const float v = h[(size_t)(g * N + nl) * D + f] * lg[nl];
        vsum += v;
        if (lm[nl] != 0.f) vmax = fmaxf(vmax, v);
    }
    smax[sub][f] = vmax;
    ssum[sub][f] = vsum;
    __syncthreads();
    if (t < 128) {
        float m = smax[0][t], s = ssum[0][t];
        #pragma unroll
        for (int k = 1; k < 8; ++k) { m = fmaxf(m, smax[k][t]); s += ssum[k][t]; }
        xout[g * 256 + t] = m;
        xout[g * 256 + 128 + t] = s * invK;
    }
}

// ---------------------------------------------------------------------------
// MLP head: z = X1+X2 (256) -> relu(z@lw1+lb1) (128) -> relu(@lw2+lb2) (64)
// -> sigmoid(@lw3+lb3) (1). One block (128 threads) per graph.
// ---------------------------------------------------------------------------
__global__ __launch_bounds__(128) void k_mlp(const float* __restrict__ X1,
                                             const float* __restrict__ X2,
                                             const float* __restrict__ lw1,
                                             const float* __restrict__ lb1,
                                             const float* __restrict__ lw2,
                                             const float* __restrict__ lb2,
                                             const float* __restrict__ lw3,
                                             const float* __restrict__ lb3,
                                             float* __restrict__ out) {
    __shared__ float z[256];
    __shared__ float o1[128];
    __shared__ float o2p[64];
    const int g = blockIdx.x, t = threadIdx.x;
    z[t] = X1[g * 256 + t] + X2[g * 256 + t];
    z[t + 128] = X1[g * 256 + 128 + t] + X2[g * 256 + 128 + t];
    __syncthreads();
    float a = lb1[t];
    for (int i = 0; i < 256; ++i) a = fmaf(z[i], lw1[i * 128 + t], a);
    o1[t] = fmaxf(a, 0.f);
    __syncthreads();
    if (t < 64) {
        float b = lb2[t];
        for (int i = 0; i < 128; ++i) b = fmaf(o1[i], lw2[i * 64 + t], b);
        o2p[t] = fmaxf(b, 0.f) * lw3[t];
    }
    __syncthreads();
    if (t == 0) {
        float sacc = lb3[0];
        for (int i = 0; i < 64; ++i) sacc += o2p[i];
        out[g] = 1.f / (1.f + expf(-sacc));
    }
}

// ---------------------------------------------------------------------------
extern "C" void kernel_launch(void* const* d_in, const int* in_sizes, int n_in,
                              void* d_out, int out_size, void* d_ws, size_t ws_size,
                              hipStream_t stream) {
    const float* x    = (const float*)d_in[0];
    const int*   ei   = (const int*)d_in[1];
    const float* W1r  = (const float*)d_in[2];
    const float* W1n  = (const float*)d_in[3];
    const float* b1   = (const float*)d_in[4];
    const float* p1   = (const float*)d_in[5];
    const float* W2r  = (const float*)d_in[6];
    const float* W2n  = (const float*)d_in[7];
    const float* b2   = (const float*)d_in[8];
    const float* p2   = (const float*)d_in[9];
    const float* lw1  = (const float*)d_in[10];
    const float* lb1  = (const float*)d_in[11];
    const float* lw2  = (const float*)d_in[12];
    const float* lb2  = (const float*)d_in[13];
    const float* lw3  = (const float*)d_in[14];
    const float* lb3  = (const float*)d_in[15];
    float* out = (float*)d_out;

    // Workspace layout (~115 MB total)
    char* w = (char*)d_ws;
    float* h1  = (float*)w; w += (size_t)NN * D * 4;
    float* h2  = (float*)w; w += (size_t)NN * D * 4;
    float* agg = (float*)w; w += (size_t)NN * D * 4;
    int* coff  = (int*)w;   w += (size_t)NN * 4;
    int* ccnt  = (int*)w;   w += (size_t)NN * 4;
    int* csrc  = (int*)w;   w += (size_t)E * 4;
    int* csrcp = (int*)w;   w += (size_t)NN * PADDEG * 4;
    float* sun = (float*)w; w += (size_t)NN * 4;
    float* g1  = (float*)w; w += (size_t)NN * 4;
    float* m1  = (float*)w; w += (size_t)NN * 4;
    float* g2  = (float*)w; w += (size_t)NN * 4;
    float* m2  = (float*)w; w += (size_t)NN * 4;
    float* X1  = (float*)w; w += (size_t)B * 256 * 4;
    float* X2  = (float*)w; w += (size_t)B * 256 * 4;

    // Build CSR (variable + padded) once; shared by both convs
    k_csr2<<<B, 512, 0, stream>>>(ei, coff, ccnt, csrc, csrcp);

    // conv1: h1 = relu(x@W1r + agg(x)@W1n + b1); s1 = h1.p1
    k_gather<<<2048, 256, 0, stream>>>(x, nullptr, coff, ccnt, csrc, csrcp, agg);
    k_gemm<<<NN / 128, 256, 0, stream>>>(x, nullptr, agg, W1r, W1n, b1, p1, h1, sun);
    k_topk_readout<<<B, 1024, 0, stream>>>(sun, p1, nullptr, K1, 1.0f / (float)K1, h1, g1, m1, X1);

    // conv2: h2 = relu((h1.*g1)@W2r + agg(h1.*g1)@W2n + b2); s2 = h2.p2
    k_gather<<<2048, 256, 0, stream>>>(h1, g1, coff, ccnt, csrc, csrcp, agg);
    k_gemm<<<NN / 128, 256, 0, stream>>>(h1, g1, agg, W2r, W2n, b2, p2, h2, sun);
    k_topk_readout<<<B, 1024, 0, stream>>>(sun, p2, m1, K2, 1.0f / (float)K2, h2, g2, m2, X2);

    // MLP head
    k_mlp<<<B, 128, 0, stream>>>(X1, X2, lw1, lb1, lw2, lb2, lw3, lb3, out);
}

// Round 5
// 300.451 us; speedup vs baseline: 1.7422x; 1.2186x over previous
//
#include <hip/hip_runtime.h>
#include <math.h>

// Problem constants (match reference)
constexpr int B = 128;
constexpr int N = 512;
constexpr int DEG = 8;
constexpr int D = 128;
constexpr int E = B * N * DEG;         // 524288
constexpr int EPG = N * DEG;           // 4096 edges per graph
constexpr int NN = B * N;              // 65536 total nodes
constexpr int K1 = 410;                // ceil(0.8*512)
constexpr int K2 = 328;                // ceil(0.8*410)
constexpr int PADDEG = 16;             // fixed-degree padding for gather

typedef __attribute__((ext_vector_type(8))) short short8;
typedef __attribute__((ext_vector_type(4))) float f32x4;

__device__ __forceinline__ unsigned short f2bf(float f) {
    unsigned int u = __float_as_uint(f);
    unsigned int r = (u + 0x7fffu + ((u >> 16) & 1u)) >> 16;   // RNE
    return (unsigned short)r;
}
__device__ __forceinline__ float bf2f(unsigned short h) {
    return __uint_as_float(((unsigned int)h) << 16);
}

// ---------------------------------------------------------------------------
// Weight prep: W[k][n] fp32 -> W^T[n][k] split into bf16 hi/lo.
// wt layout: matrix m at wt + m*32768; hi at +0 (16384), lo at +16384.
// ---------------------------------------------------------------------------
__global__ __launch_bounds__(256) void k_prepw(const float* __restrict__ W0,
                                               const float* __restrict__ W1,
                                               const float* __restrict__ W2,
                                               const float* __restrict__ W3,
                                               unsigned short* __restrict__ wt) {
    const float* Ws[4] = {W0, W1, W2, W3};
    const int m = blockIdx.x;
    const float* src = Ws[m];
    unsigned short* dH = wt + (size_t)m * 32768;
    unsigned short* dL = dH + 16384;
    for (int idx = threadIdx.x; idx < 16384; idx += 256) {
        int kk = idx >> 7, n = idx & 127;
        float v = src[idx];                 // [k][n] row-major
        unsigned short h = f2bf(v);
        unsigned short l = f2bf(v - bf2f(h));
        dH[n * 128 + kk] = h;               // transposed [n][k]
        dL[n * 128 + kk] = l;
    }
}

// ---------------------------------------------------------------------------
// CSR build: per-graph counting sort of edges by dst. One block per graph.
// Variable CSR (coff/ccnt/csrc) + padded fixed-degree(16) csrcp
// (pad slots = self-index; gather skips them via deg guard).
// ---------------------------------------------------------------------------
__global__ __launch_bounds__(512) void k_csr2(const int* __restrict__ ei,
                                              int* __restrict__ coff,
                                              int* __restrict__ ccnt,
                                              int* __restrict__ csrc,
                                              int* __restrict__ csrcp) {
    __shared__ int cnt[512];
    __shared__ int sa[512];
    __shared__ int offs[512];
    __shared__ int cur[512];
    const int g = blockIdx.x, t = threadIdx.x;
    const int base = g * N;
    const int* srcs = ei + g * EPG;          // ei[0:E] = src
    const int* dsts = ei + E + g * EPG;      // ei[E:2E] = dst
    {
        const int n = base + t;
        int4 self = make_int4(n, n, n, n);
        #pragma unroll
        for (int k4 = 0; k4 < PADDEG / 4; ++k4)
            *(int4*)&csrcp[(size_t)n * PADDEG + k4 * 4] = self;
    }
    cnt[t] = 0;
    __syncthreads();
    #pragma unroll
    for (int e = t; e < EPG; e += 512)
        atomicAdd(&cnt[dsts[e] - base], 1);
    __syncthreads();
    int v = cnt[t];
    sa[t] = v;
    __syncthreads();
    for (int d = 1; d < 512; d <<= 1) {
        int add = (t >= d) ? sa[t - d] : 0;
        __syncthreads();
        sa[t] += add;
        __syncthreads();
    }
    const int excl = sa[t] - v;              // exclusive prefix within graph
    offs[t] = excl;
    cur[t] = excl;
    coff[base + t] = g * EPG + excl;
    ccnt[base + t] = v;
    __syncthreads();
    #pragma unroll
    for (int e = t; e < EPG; e += 512) {
        int d = dsts[e] - base;
        int pos = atomicAdd(&cur[d], 1);     // graph-global slot
        int s = srcs[e];
        csrc[g * EPG + pos] = s;
        int lpos = pos - offs[d];            // node-local slot
        if (lpos < PADDEG) csrcp[(size_t)(base + d) * PADDEG + lpos] = s;
    }
}

// ---------------------------------------------------------------------------
// Gather-sum via padded CSR. All 16 idx preloaded (independent loads);
// per-k guard (k<deg) is uniform per 32-lane half-wave -> skipped loads are
// cheap and pad traffic is eliminated. 2048 blocks x 256 threads.
// ---------------------------------------------------------------------------
__global__ __launch_bounds__(256, 2) void k_gather(const float* __restrict__ feat,
                                                   const float* __restrict__ gate,
                                                   const int* __restrict__ coff,
                                                   const int* __restrict__ ccnt,
                                                   const int* __restrict__ csrc,
                                                   const int* __restrict__ csrcp,
                                                   float* __restrict__ aggout) {
    const int bid = blockIdx.x;
    const int xcd = bid & 7;
    const int j = bid >> 3;                  // 0..255
    const int g = ((j & 15) << 3) | xcd;     // fixed xcd per graph
    const int chunk = j >> 4;                // 0..15, 32 nodes per chunk
    const int t = threadIdx.x;
    const int lane = t & 31, grp = t >> 5;
    const int fo = lane * 4;
    #pragma unroll
    for (int it = 0; it < 4; ++it) {
        const int n = g * N + chunk * 32 + it * 8 + grp;
        const int deg = ccnt[n];
        int idx[PADDEG];
        *(int4*)&idx[0]  = *(const int4*)&csrcp[(size_t)n * PADDEG + 0];
        *(int4*)&idx[4]  = *(const int4*)&csrcp[(size_t)n * PADDEG + 4];
        *(int4*)&idx[8]  = *(const int4*)&csrcp[(size_t)n * PADDEG + 8];
        *(int4*)&idx[12] = *(const int4*)&csrcp[(size_t)n * PADDEG + 12];
        float4 acc = make_float4(0.f, 0.f, 0.f, 0.f);
        #pragma unroll
        for (int k = 0; k < PADDEG; ++k) {
            if (k < deg) {                   // uniform per half-wave
                float wk = gate ? gate[idx[k]] : 1.0f;
                float4 v = *(const float4*)&feat[(size_t)idx[k] * D + fo];
                acc.x = fmaf(v.x, wk, acc.x);
                acc.y = fmaf(v.y, wk, acc.y);
                acc.z = fmaf(v.z, wk, acc.z);
                acc.w = fmaf(v.w, wk, acc.w);
            }
        }
        if (deg > PADDEG) {                  // rare tail
            const int start = coff[n];
            for (int k = PADDEG; k < deg; ++k) {
                int ix = csrc[start + k];
                float gt = gate ? gate[ix] : 1.0f;
                float4 v = *(const float4*)&feat[(size_t)ix * D + fo];
                acc.x = fmaf(v.x, gt, acc.x);
                acc.y = fmaf(v.y, gt, acc.y);
                acc.z = fmaf(v.z, gt, acc.z);
                acc.w = fmaf(v.w, gt, acc.w);
            }
        }
        *(float4*)&aggout[(size_t)n * D + fo] = acc;
    }
}

// ---------------------------------------------------------------------------
// MFMA conv GEMM (bf16 hi/lo split, 3-product): out = relu((A0.*g)@W0 +
// A1@W1 + b), sun[row] = out[row,:].pvec.
// BM=BN=128, BK=32; 256 thr = 4 waves, each 64x64 via 4x4 tiles of
// mfma_f32_16x16x32_bf16. A split on the fly; W pre-split/transposed.
// ---------------------------------------------------------------------------
__global__ __launch_bounds__(256, 2) void k_gemm(const float* __restrict__ A0,
                                                 const float* __restrict__ gateA,
                                                 const float* __restrict__ A1,
                                                 const unsigned short* __restrict__ W0t,
                                                 const unsigned short* __restrict__ W1t,
                                                 const float* __restrict__ bias,
                                                 const float* __restrict__ pvec,
                                                 float* __restrict__ out,
                                                 float* __restrict__ sun) {
    __shared__ unsigned short AsH[128 * 40], AsL[128 * 40];
    __shared__ unsigned short BsH[128 * 40], BsL[128 * 40];
    __shared__ float red[128 * 33];
    const int t = threadIdx.x;
    const int r0 = blockIdx.x * 128;
    const int w = t >> 6, lane = t & 63;
    const int lr = lane & 15, kg = (lane >> 4) * 8;
    const int wm = (w >> 1) * 64, wn = (w & 1) * 64;
    const int arow = t >> 1, kb = (t & 1) * 16;     // A staging
    const float ga = gateA ? gateA[r0 + arow] : 1.0f;

    f32x4 acc[4][4];
    #pragma unroll
    for (int mt = 0; mt < 4; ++mt)
        #pragma unroll
        for (int nt = 0; nt < 4; ++nt)
            acc[mt][nt] = (f32x4)(0.f);

    for (int phase = 0; phase < 2; ++phase) {
        const float* Ap = phase ? A1 : A0;
        const unsigned short* WH = phase ? W1t : W0t;
        const unsigned short* WL = WH + 16384;
        const float gmul = phase ? 1.0f : ga;
        for (int c = 0; c < 4; ++c) {
            const int k0 = c * 32;
            __syncthreads();                 // previous chunk fully consumed
            // --- A stage: fp32 -> hi/lo bf16, layout [row][k] stride 40
            #pragma unroll
            for (int i = 0; i < 4; ++i) {
                float4 av = *(const float4*)&Ap[(size_t)(r0 + arow) * D + k0 + kb + i * 4];
                av.x *= gmul; av.y *= gmul; av.z *= gmul; av.w *= gmul;
                unsigned int h0 = f2bf(av.x), h1 = f2bf(av.y), h2 = f2bf(av.z), h3 = f2bf(av.w);
                uint2 ph; ph.x = h0 | (h1 << 16); ph.y = h2 | (h3 << 16);
                *(uint2*)&AsH[arow * 40 + kb + i * 4] = ph;
                unsigned int l0 = f2bf(av.x - bf2f(h0)), l1 = f2bf(av.y - bf2f(h1));
                unsigned int l2 = f2bf(av.z - bf2f(h2)), l3 = f2bf(av.w - bf2f(h3));
                uint2 pl; pl.x = l0 | (l1 << 16); pl.y = l2 | (l3 << 16);
                *(uint2*)&AsL[arow * 40 + kb + i * 4] = pl;
            }
            // --- B stage: copy pre-split W^T[n][k] chunk, stride 40
            {
                const int part = t & 3;
                #pragma unroll
                for (int rep = 0; rep < 2; ++rep) {
                    const int n = (t >> 2) + rep * 64;
                    *(int4*)&BsH[n * 40 + part * 8] = *(const int4*)&WH[n * 128 + k0 + part * 8];
                    *(int4*)&BsL[n * 40 + part * 8] = *(const int4*)&WL[n * 128 + k0 + part * 8];
                }
            }
            __syncthreads();
            // --- fragments + MFMA
            short8 aH[4], aL[4], bH[4], bL[4];
            #pragma unroll
            for (int mt = 0; mt < 4; ++mt) {
                aH[mt] = *(const short8*)&AsH[(wm + mt * 16 + lr) * 40 + kg];
                aL[mt] = *(const short8*)&AsL[(wm + mt * 16 + lr) * 40 + kg];
            }
            #pragma unroll
            for (int nt = 0; nt < 4; ++nt) {
                bH[nt] = *(const short8*)&BsH[(wn + nt * 16 + lr) * 40 + kg];
                bL[nt] = *(const short8*)&BsL[(wn + nt * 16 + lr) * 40 + kg];
            }
            #pragma unroll
            for (int mt = 0; mt < 4; ++mt)
                #pragma unroll
                for (int nt = 0; nt < 4; ++nt) {
                    acc[mt][nt] = __builtin_amdgcn_mfma_f32_16x16x32_bf16(aH[mt], bH[nt], acc[mt][nt], 0, 0, 0);
                    acc[mt][nt] = __builtin_amdgcn_mfma_f32_16x16x32_bf16(aH[mt], bL[nt], acc[mt][nt], 0, 0, 0);
                    acc[mt][nt] = __builtin_amdgcn_mfma_f32_16x16x32_bf16(aL[mt], bH[nt], acc[mt][nt], 0, 0, 0);
                }
        }
    }
    // --- Epilogue: bias + relu + store + score partials
    float bb[4], pv[4];
    #pragma unroll
    for (int nt = 0; nt < 4; ++nt) {
        bb[nt] = bias[wn + nt * 16 + lr];
        pv[nt] = pvec[wn + nt * 16 + lr];
    }
    #pragma unroll
    for (int mt = 0; mt < 4; ++mt) {
        #pragma unroll
        for (int r = 0; r < 4; ++r) {
            const int rowl = wm + mt * 16 + (lane >> 4) * 4 + r;
            const int row = r0 + rowl;
            float part = 0.f;
            #pragma unroll
            for (int nt = 0; nt < 4; ++nt) {
                float v = acc[mt][nt][r] + bb[nt];
                v = fmaxf(v, 0.f);
                out[(size_t)row * D + wn + nt * 16 + lr] = v;
                part = fmaf(v, pv[nt], part);
            }
            red[rowl * 33 + (w & 1) * 16 + lr] = part;   // unique slot per lane
        }
    }
    __syncthreads();
    if (t < 128) {
        float s = 0.f;
        #pragma unroll
        for (int j = 0; j < 32; ++j) s += red[t * 33 + j];
        sun[r0 + t] = s;
    }
}

// ---------------------------------------------------------------------------
// Fused per-graph TopK + readout, 2 blocks per graph (feature halves).
// TopK rank matches jax.lax.top_k stable order; gate = tanh(s/||p||)*keep.
// Both blocks of a graph compute identical gates (benign duplicate writes).
// ---------------------------------------------------------------------------
__global__ __launch_bounds__(1024) void k_topk_readout(const float* __restrict__ sun,
                                                       const float* __restrict__ p,
                                                       const float* __restrict__ prevmask,
                                                       int K, float invK,
                                                       const float* __restrict__ h,
                                                       float* __restrict__ gate,
                                                       float* __restrict__ mask,
                                                       float* __restrict__ xout) {
    __shared__ float ls[512];
    __shared__ float lg[512];
    __shared__ float lm[512];
    __shared__ float red[128];
    __shared__ float smax[16][64];
    __shared__ float ssum[16][64];
    __shared__ float norm_s;
    const int bid = blockIdx.x;
    const int g = bid >> 1, half = bid & 1;
    const int t = threadIdx.x;
    if (t < 512) {
        const int n = g * N + t;
        float s = sun[n];
        if (prevmask && prevmask[n] == 0.0f) s = -INFINITY;
        ls[t] = s;
    }
    if (t < 128) { float pvv = p[t]; red[t] = pvv * pvv; }
    __syncthreads();
    if (t < 64) red[t] += red[t + 64];
    __syncthreads();
    if (t < 32) red[t] += red[t + 32];
    __syncthreads();
    if (t == 0) {
        float s = 0.f;
        #pragma unroll
        for (int i = 0; i < 32; ++i) s += red[i];
        norm_s = sqrtf(s);
    }
    __syncthreads();
    if (t < 512) {
        const float s = ls[t];
        int cnt = 0;
        for (int jj = 0; jj < 512; ++jj) {
            float sj = ls[jj];
            cnt += (sj > s || (sj == s && jj < t)) ? 1 : 0;
        }
        const bool keep = cnt < K;
        const float gv = keep ? tanhf(s / norm_s) : 0.0f;
        const float mv = keep ? 1.0f : 0.0f;
        lg[t] = gv; lm[t] = mv;
        gate[g * N + t] = gv; mask[g * N + t] = mv;
    }
    __syncthreads();
    const int f = half * 64 + (t & 63), sub = t >> 6;   // 16 subsets x 64 feats
    float vmax = -INFINITY, vsum = 0.f;
    for (int nl = sub; nl < N; nl += 16) {
        const float v = h[(size_t)(g * N + nl) * D + f] * lg[nl];
        vsum += v;
        if (lm[nl] != 0.f) vmax = fmaxf(vmax, v);
    }
    smax[sub][t & 63] = vmax;
    ssum[sub][t & 63] = vsum;
    __syncthreads();
    if (t < 64) {
        float m = smax[0][t], s = ssum[0][t];
        #pragma unroll
        for (int k = 1; k < 16; ++k) { m = fmaxf(m, smax[k][t]); s += ssum[k][t]; }
        xout[g * 256 + half * 64 + t] = m;
        xout[g * 256 + 128 + half * 64 + t] = s * invK;
    }
}

// ---------------------------------------------------------------------------
// MLP head. One block (128 threads) per graph.
// ---------------------------------------------------------------------------
__global__ __launch_bounds__(128) void k_mlp(const float* __restrict__ X1,
                                             const float* __restrict__ X2,
                                             const float* __restrict__ lw1,
                                             const float* __restrict__ lb1,
                                             const float* __restrict__ lw2,
                                             const float* __restrict__ lb2,
                                             const float* __restrict__ lw3,
                                             const float* __restrict__ lb3,
                                             float* __restrict__ out) {
    __shared__ float z[256];
    __shared__ float o1[128];
    __shared__ float o2p[64];
    const int g = blockIdx.x, t = threadIdx.x;
    z[t] = X1[g * 256 + t] + X2[g * 256 + t];
    z[t + 128] = X1[g * 256 + 128 + t] + X2[g * 256 + 128 + t];
    __syncthreads();
    float a = lb1[t];
    for (int i = 0; i < 256; ++i) a = fmaf(z[i], lw1[i * 128 + t], a);
    o1[t] = fmaxf(a, 0.f);
    __syncthreads();
    if (t < 64) {
        float b = lb2[t];
        for (int i = 0; i < 128; ++i) b = fmaf(o1[i], lw2[i * 64 + t], b);
        o2p[t] = fmaxf(b, 0.f) * lw3[t];
    }
    __syncthreads();
    if (t == 0) {
        float sacc = lb3[0];
        for (int i = 0; i < 64; ++i) sacc += o2p[i];
        out[g] = 1.f / (1.f + expf(-sacc));
    }
}

// ---------------------------------------------------------------------------
extern "C" void kernel_launch(void* const* d_in, const int* in_sizes, int n_in,
                              void* d_out, int out_size, void* d_ws, size_t ws_size,
                              hipStream_t stream) {
    const float* x    = (const float*)d_in[0];
    const int*   ei   = (const int*)d_in[1];
    const float* W1r  = (const float*)d_in[2];
    const float* W1n  = (const float*)d_in[3];
    const float* b1   = (const float*)d_in[4];
    const float* p1   = (const float*)d_in[5];
    const float* W2r  = (const float*)d_in[6];
    const float* W2n  = (const float*)d_in[7];
    const float* b2   = (const float*)d_in[8];
    const float* p2   = (const float*)d_in[9];
    const float* lw1  = (const float*)d_in[10];
    const float* lb1  = (const float*)d_in[11];
    const float* lw2  = (const float*)d_in[12];
    const float* lb2  = (const float*)d_in[13];
    const float* lw3  = (const float*)d_in[14];
    const float* lb3  = (const float*)d_in[15];
    float* out = (float*)d_out;

    // Workspace layout (~116 MB total)
    char* w = (char*)d_ws;
    float* h1  = (float*)w; w += (size_t)NN * D * 4;
    float* h2  = (float*)w; w += (size_t)NN * D * 4;
    float* agg = (float*)w; w += (size_t)NN * D * 4;
    int* coff  = (int*)w;   w += (size_t)NN * 4;
    int* ccnt  = (int*)w;   w += (size_t)NN * 4;
    int* csrc  = (int*)w;   w += (size_t)E * 4;
    int* csrcp = (int*)w;   w += (size_t)NN * PADDEG * 4;
    unsigned short* wt = (unsigned short*)w; w += (size_t)4 * 2 * 16384 * 2;  // 4 mats x hi/lo x 16384 ushort
    float* sun = (float*)w; w += (size_t)NN * 4;
    float* g1  = (float*)w; w += (size_t)NN * 4;
    float* m1  = (float*)w; w += (size_t)NN * 4;
    float* g2  = (float*)w; w += (size_t)NN * 4;
    float* m2  = (float*)w; w += (size_t)NN * 4;
    float* X1  = (float*)w; w += (size_t)B * 256 * 4;
    float* X2  = (float*)w; w += (size_t)B * 256 * 4;

    const unsigned short* wt1r = wt;                 // slot 0: W1r
    const unsigned short* wt1n = wt + 1 * 32768;     // slot 1: W1n
    const unsigned short* wt2r = wt + 2 * 32768;     // slot 2: W2r
    const unsigned short* wt2n = wt + 3 * 32768;     // slot 3: W2n

    // One-time prep: weights split/transpose + CSR build
    k_prepw<<<4, 256, 0, stream>>>(W1r, W1n, W2r, W2n, wt);
    k_csr2<<<B, 512, 0, stream>>>(ei, coff, ccnt, csrc, csrcp);

    // conv1: h1 = relu(x@W1r + agg(x)@W1n + b1); s1 = h1.p1
    k_gather<<<2048, 256, 0, stream>>>(x, nullptr, coff, ccnt, csrc, csrcp, agg);
    k_gemm<<<NN / 128, 256, 0, stream>>>(x, nullptr, agg, wt1r, wt1n, b1, p1, h1, sun);
    k_topk_readout<<<2 * B, 1024, 0, stream>>>(sun, p1, nullptr, K1, 1.0f / (float)K1, h1, g1, m1, X1);

    // conv2: h2 = relu((h1.*g1)@W2r + agg(h1.*g1)@W2n + b2); s2 = h2.p2
    k_gather<<<2048, 256, 0, stream>>>(h1, g1, coff, ccnt, csrc, csrcp, agg);
    k_gemm<<<NN / 128, 256, 0, stream>>>(h1, g1, agg, wt2r, wt2n, b2, p2, h2, sun);
    k_topk_readout<<<2 * B, 1024, 0, stream>>>(sun, p2, m1, K2, 1.0f / (float)K2, h2, g2, m2, X2);

    // MLP head
    k_mlp<<<B, 128, 0, stream>>>(X1, X2, lw1, lb1, lw2, lb2, lw3, lb3, out);
}